// Round 17
// baseline (105.449 us; speedup 1.0000x reference)
//
#include <hip/hip_runtime.h>

// Sizes (fixed by the problem)
#define NB 16
#define NQ 128
#define NK 512
#define NH 128
#define NDV 128

#define KPAD 132  // 128+4 floats: b128 lane*KPAD reads measured 0 conflicts

typedef __attribute__((ext_vector_type(8))) short short8;
typedef __attribute__((ext_vector_type(4))) float f32x4;
typedef __attribute__((ext_vector_type(2))) float f32x2;

#define C2LOG2E 2.8853900817779268f  // 2*log2(e): folded into proj epilogue
#define LOG2E   1.4426950408889634f

__device__ __forceinline__ short f2bf(float x) {   // RNE f32 -> bf16
    unsigned u = __float_as_uint(x);
    unsigned r = (u + 0x7fffu + ((u >> 16) & 1u)) >> 16;
    return (short)r;
}
__device__ __forceinline__ float bf2f(short s) {
    return __uint_as_float(((unsigned)(unsigned short)s) << 16);
}

// ---------------------------------------------------------------------------
// Kernel 1: pack W into MFMA B-fragment order, split bf16 hi/lo. (round-10)
// ---------------------------------------------------------------------------
__global__ __launch_bounds__(256) void wsplit_kernel(
    const float* __restrict__ Wq, const float* __restrict__ Wk,
    const float* __restrict__ wv,
    short* __restrict__ pqh, short* __restrict__ pql,
    short* __restrict__ pkh, short* __restrict__ pkl,
    float* __restrict__ w2)
{
    int blk = blockIdx.x;          // 16 blocks = w(2) x ht(8)
    int t   = threadIdx.x;         // ks(4) x lane(64)
    if (blk == 0 && t < NH) w2[t] = 2.0f * wv[t];
    int w = blk >> 3, ht = blk & 7;
    int ks = t >> 6, lane = t & 63;
    int m = lane & 15, quad = lane >> 4;
    const float* W = w ? Wk : Wq;
    short* ph = w ? pkh : pqh;
    short* pl = w ? pkl : pql;
    short8 hi, lo;
#pragma unroll
    for (int j = 0; j < 8; ++j) {
        float x = W[(size_t)(ks * 32 + quad * 8 + j) * NH + ht * 16 + m];
        short h = f2bf(x);
        hi[j] = h;
        lo[j] = f2bf(x - bf2f(h));
    }
    size_t o = (size_t)((ht * 4 + ks) * 64 + lane) * 8;
    *(short8*)(ph + o) = hi;
    *(short8*)(pl + o) = lo;
}

// ---------------------------------------------------------------------------
// Kernel 2: projection + exp. (round-10 exact)
// ---------------------------------------------------------------------------
__global__ __launch_bounds__(256) void proj_kernel(
    const float* __restrict__ Xq, const float* __restrict__ Xk,
    const short* __restrict__ pqh, const short* __restrict__ pql,
    const short* __restrict__ pkh, const short* __restrict__ pkl,
    float* __restrict__ Eq, float* __restrict__ Ek)
{
    __shared__ float s_x[16 * KPAD];     // 8448 B

    int blk = blockIdx.x;
    const float* X; const short* ph; const short* pl; float* Y; int row0;
    if (blk < 128) { X = Xq; ph = pqh; pl = pql; Y = Eq; row0 = blk * 16; }
    else           { X = Xk; ph = pkh; pl = pkl; Y = Ek; row0 = (blk - 128) * 16; }
    int t = threadIdx.x;
    int wave = t >> 6, lane = t & 63;
    int m = lane & 15, quad = lane >> 4;

#pragma unroll
    for (int r = 0; r < 2; ++r) {
        int i = (t + r * 256) * 4;
        int row = i >> 7, col = i & 127;
        *(f32x4*)&s_x[row * KPAD + col] =
            *(const f32x4*)&X[(size_t)(row0 + row) * NH + col];
    }
    __syncthreads();

    short8 AH[4], AL[4];
#pragma unroll
    for (int ks = 0; ks < 4; ++ks) {
        int base = m * KPAD + ks * 32 + quad * 8;
        f32x4 x0 = *(const f32x4*)&s_x[base];
        f32x4 x1 = *(const f32x4*)&s_x[base + 4];
#pragma unroll
        for (int j = 0; j < 4; ++j) {
            short h0 = f2bf(x0[j]);
            AH[ks][j] = h0; AL[ks][j] = f2bf(x0[j] - bf2f(h0));
            short h1 = f2bf(x1[j]);
            AH[ks][j + 4] = h1; AL[ks][j + 4] = f2bf(x1[j] - bf2f(h1));
        }
    }
#pragma unroll
    for (int hi = 0; hi < 2; ++hi) {
        int ht = wave * 2 + hi;
        f32x4 acc = {0.f, 0.f, 0.f, 0.f};
#pragma unroll
        for (int ks = 0; ks < 4; ++ks) {
            size_t o = (size_t)((ht * 4 + ks) * 64 + lane) * 8;
            short8 bh = *(const short8*)(ph + o);
            short8 bl = *(const short8*)(pl + o);
            acc = __builtin_amdgcn_mfma_f32_16x16x32_bf16(AH[ks], bl, acc, 0, 0, 0);
            acc = __builtin_amdgcn_mfma_f32_16x16x32_bf16(AL[ks], bh, acc, 0, 0, 0);
            acc = __builtin_amdgcn_mfma_f32_16x16x32_bf16(AH[ks], bh, acc, 0, 0, 0);
        }
        // D: col = lane&15, row = quad*4 + r  [verified layout]
#pragma unroll
        for (int r = 0; r < 4; ++r)
            Y[(size_t)(row0 + quad * 4 + r) * NH + ht * 16 + m] =
                __builtin_amdgcn_exp2f(acc[r] * C2LOG2E);
    }
}

// ---------------------------------------------------------------------------
// Kernel 3: scores. (round-16 exact: packed-f32 inner loop, -2.8us measured)
// ---------------------------------------------------------------------------
__global__ __launch_bounds__(512) void score_kernel(
    const float* __restrict__ Eqp, const float* __restrict__ Ekp,
    const int* __restrict__ vlen, const float* __restrict__ w2,
    float* __restrict__ P)
{
    __shared__ float s_ek[128 * KPAD];   // 67584 B
    __shared__ float s_eq[16 * NH];      //  8192 B
    __shared__ float s_w2[NH];           //   512 B

    int blk = blockIdx.x;
    int b    = blk & 15;                 // batch-interleaved
    int rest = blk >> 4;
    int qt = rest & 7, kc = rest >> 3;   // qt 0..7 (16q each), kc 0..3 (128k)
    int q0 = qt * 16, k0 = kc * 128;
    int t  = threadIdx.x;

    int nv = vlen[b];
    nv = max(1, min(NK, nv));
    float* Pb = P + ((size_t)b * NQ + q0) * NK;

    if (k0 >= nv) {
        // fully masked chunk: 16q x 128k = 2048 floats = one f32x4/thread
        int q = t >> 5, kk = (t & 31) * 4;
        f32x4 z = {0.f, 0.f, 0.f, 0.f};
        *(f32x4*)&Pb[(size_t)q * NK + k0 + kk] = z;
        return;
    }

    for (int i = t; i < 128 * 32; i += 512) {
        int row = i >> 5, c4 = i & 31;
        *(f32x4*)&s_ek[row * KPAD + c4 * 4] =
            *(const f32x4*)&Ekp[((size_t)b * NK + k0 + row) * NH + c4 * 4];
    }
    *(f32x4*)&s_eq[t * 4] =
        *(const f32x4*)&Eqp[((size_t)b * NQ + q0) * NH + t * 4];
    if (t < 32) *(f32x4*)&s_w2[t * 4] = *(const f32x4*)&w2[t * 4];
    __syncthreads();

    int lane = t & 63, w = t >> 6;
    int g = w & 3, hf = w >> 2;

    // Wsum = sum_h wv = 0.5 * sum_h w2
    float s2 = s_w2[lane] + s_w2[lane + 64];
#pragma unroll
    for (int off = 32; off; off >>= 1) s2 += __shfl_xor(s2, off);
    float wsum = 0.5f * s2;

    const float* ek = &s_ek[(hf * 64 + lane) * KPAD];
    const float* e0 = &s_eq[(g * 4 + 0) * NH];
    const float* e1 = &s_eq[(g * 4 + 1) * NH];
    const float* e2 = &s_eq[(g * 4 + 2) * NH];
    const float* e3 = &s_eq[(g * 4 + 3) * NH];

    const f32x2 one2 = {1.0f, 1.0f};
    f32x2 v00 = {0.f, 0.f}, v01 = {0.f, 0.f};
    f32x2 v10 = {0.f, 0.f}, v11 = {0.f, 0.f};
    f32x2 v20 = {0.f, 0.f}, v21 = {0.f, 0.f};
    f32x2 v30 = {0.f, 0.f}, v31 = {0.f, 0.f};

#define PKSTEP(accv, qv, kv, wv)                                        \
    {                                                                   \
        f32x2 x = qv * kv + one2;                                       \
        float R = __builtin_amdgcn_rcpf(x[0] * x[1]);                   \
        f32x2 xs = {x[1], x[0]};                                        \
        accv += wv * (R * xs);                                          \
    }

#pragma unroll
    for (int hh = 0; hh < NH; hh += 8) {
        f32x4 kAv = *(const f32x4*)(ek + hh);
        f32x4 kBv = *(const f32x4*)(ek + hh + 4);
        f32x4 wAv = *(const f32x4*)(s_w2 + hh);
        f32x4 wBv = *(const f32x4*)(s_w2 + hh + 4);
        f32x2 kA0 = {kAv[0], kAv[1]}, kA1 = {kAv[2], kAv[3]};
        f32x2 kB0 = {kBv[0], kBv[1]}, kB1 = {kBv[2], kBv[3]};
        f32x2 wA0 = {wAv[0], wAv[1]}, wA1 = {wAv[2], wAv[3]};
        f32x2 wB0 = {wBv[0], wBv[1]}, wB1 = {wBv[2], wBv[3]};
        {
            f32x4 qa = *(const f32x4*)(e0 + hh), qb = *(const f32x4*)(e0 + hh + 4);
            f32x2 qa0 = {qa[0], qa[1]}, qa1 = {qa[2], qa[3]};
            f32x2 qb0 = {qb[0], qb[1]}, qb1 = {qb[2], qb[3]};
            PKSTEP(v00, qa0, kA0, wA0); PKSTEP(v01, qa1, kA1, wA1);
            PKSTEP(v00, qb0, kB0, wB0); PKSTEP(v01, qb1, kB1, wB1);
        }
        {
            f32x4 qa = *(const f32x4*)(e1 + hh), qb = *(const f32x4*)(e1 + hh + 4);
            f32x2 qa0 = {qa[0], qa[1]}, qa1 = {qa[2], qa[3]};
            f32x2 qb0 = {qb[0], qb[1]}, qb1 = {qb[2], qb[3]};
            PKSTEP(v10, qa0, kA0, wA0); PKSTEP(v11, qa1, kA1, wA1);
            PKSTEP(v10, qb0, kB0, wB0); PKSTEP(v11, qb1, kB1, wB1);
        }
        {
            f32x4 qa = *(const f32x4*)(e2 + hh), qb = *(const f32x4*)(e2 + hh + 4);
            f32x2 qa0 = {qa[0], qa[1]}, qa1 = {qa[2], qa[3]};
            f32x2 qb0 = {qb[0], qb[1]}, qb1 = {qb[2], qb[3]};
            PKSTEP(v20, qa0, kA0, wA0); PKSTEP(v21, qa1, kA1, wA1);
            PKSTEP(v20, qb0, kB0, wB0); PKSTEP(v21, qb1, kB1, wB1);
        }
        {
            f32x4 qa = *(const f32x4*)(e3 + hh), qb = *(const f32x4*)(e3 + hh + 4);
            f32x2 qa0 = {qa[0], qa[1]}, qa1 = {qa[2], qa[3]};
            f32x2 qb0 = {qb[0], qb[1]}, qb1 = {qb[2], qb[3]};
            PKSTEP(v30, qa0, kA0, wA0); PKSTEP(v31, qa1, kA1, wA1);
            PKSTEP(v30, qb0, kB0, wB0); PKSTEP(v31, qb1, kB1, wB1);
        }
    }
#undef PKSTEP
    float c0 = (v00[0] + v00[1]) + (v01[0] + v01[1]);
    float c1 = (v10[0] + v10[1]) + (v11[0] + v11[1]);
    float c2 = (v20[0] + v20[1]) + (v21[0] + v21[1]);
    float c3 = (v30[0] + v30[1]) + (v31[0] + v31[1]);
    int kg = k0 + hf * 64 + lane;
    bool valid = kg < nv;
    float p0 = valid ? __builtin_amdgcn_exp2f((wsum - c0) * LOG2E) : 0.f;
    float p1 = valid ? __builtin_amdgcn_exp2f((wsum - c1) * LOG2E) : 0.f;
    float p2 = valid ? __builtin_amdgcn_exp2f((wsum - c2) * LOG2E) : 0.f;
    float p3 = valid ? __builtin_amdgcn_exp2f((wsum - c3) * LOG2E) : 0.f;
    float* Pr = Pb + (size_t)(g * 4) * NK + kg;
    Pr[0 * NK] = p0;                     // coalesced dword stores per q-row
    Pr[1 * NK] = p1;
    Pr[2 * NK] = p2;
    Pr[3 * NK] = p3;
}

// ---------------------------------------------------------------------------
// Kernel 4: normalize + AV. r10 structure; inner loop now f32x4 VECTOR
// expressions (splatted P-weights) -> v_pk_fma_f32: 32 pk-fma per 8k iter
// instead of 64 scalar v_fmac. Same fma tree per output (numerics identical).
// ---------------------------------------------------------------------------
__global__ __launch_bounds__(256) void av_kernel(
    const float* __restrict__ P, const float* __restrict__ V,
    const int* __restrict__ vlen, float* __restrict__ out)
{
    __shared__ float s_p[8 * NK];        // 16 KB

    int blk = blockIdx.x;
    int b = blk & 15, qt = blk >> 4;     // qt 0..15 (8 q each)
    int q0 = qt * 8;
    int t = threadIdx.x;

    int nv = vlen[b];
    nv = max(1, min(NK, nv));
    int nv8 = (nv + 7) & ~7;

    const f32x4* Pv = (const f32x4*)(P + ((size_t)b * NQ + q0) * NK);
#pragma unroll
    for (int r = 0; r < 4; ++r)
        ((f32x4*)s_p)[t + r * 256] = Pv[t + r * 256];
    __syncthreads();

    int lane = t & 63, w = t >> 6;
    int qa = w * 2, qb = qa + 1;
    const float* pa = &s_p[qa * NK];
    const float* pb = &s_p[qb * NK];

    // row sums (zeros beyond nv included -> exact)
    f32x4 sa0 = *(const f32x4*)(pa + lane * 8);
    f32x4 sa1 = *(const f32x4*)(pa + lane * 8 + 4);
    f32x4 sb0 = *(const f32x4*)(pb + lane * 8);
    f32x4 sb1 = *(const f32x4*)(pb + lane * 8 + 4);
    float sa = ((sa0[0] + sa0[1]) + (sa0[2] + sa0[3])) +
               ((sa1[0] + sa1[1]) + (sa1[2] + sa1[3]));
    float sb = ((sb0[0] + sb0[1]) + (sb0[2] + sb0[3])) +
               ((sb1[0] + sb1[1]) + (sb1[2] + sb1[3]));
#pragma unroll
    for (int off = 32; off; off >>= 1) {
        sa += __shfl_xor(sa, off);
        sb += __shfl_xor(sb, off);
    }
    float ra = 1.0f / sa, rb = 1.0f / sb;

    int par = lane >> 5;                 // k parity for this half-wave
    int dl  = lane & 31;
    int dv0 = dl * 4;                    // 4 dv per lane (f32x4)
    const float* Vb = V + (size_t)b * NK * NDV + dv0;
    f32x4 Oa = {0.f, 0.f, 0.f, 0.f};
    f32x4 Ob = {0.f, 0.f, 0.f, 0.f};
#define SPLAT4(x) {x, x, x, x}
    for (int k = 0; k < nv8; k += 8) {
        f32x4 pA0 = *(const f32x4*)(pa + k);         // LDS broadcasts
        f32x4 pA1 = *(const f32x4*)(pa + k + 4);
        f32x4 pB0 = *(const f32x4*)(pb + k);
        f32x4 pB1 = *(const f32x4*)(pb + k + 4);
        f32x4 v0 = *(const f32x4*)(Vb + (size_t)(k + 0 + par) * NDV);
        f32x4 v1 = *(const f32x4*)(Vb + (size_t)(k + 2 + par) * NDV);
        f32x4 v2 = *(const f32x4*)(Vb + (size_t)(k + 4 + par) * NDV);
        f32x4 v3 = *(const f32x4*)(Vb + (size_t)(k + 6 + par) * NDV);
        f32x4 a0 = SPLAT4(pA0[par]), a1 = SPLAT4(pA0[2 + par]);
        f32x4 a2 = SPLAT4(pA1[par]), a3 = SPLAT4(pA1[2 + par]);
        f32x4 b0 = SPLAT4(pB0[par]), b1 = SPLAT4(pB0[2 + par]);
        f32x4 b2 = SPLAT4(pB1[par]), b3 = SPLAT4(pB1[2 + par]);
        Oa += a0 * v0; Ob += b0 * v0;    // -> v_pk_fma_f32 pairs
        Oa += a1 * v1; Ob += b1 * v1;
        Oa += a2 * v2; Ob += b2 * v2;
        Oa += a3 * v3; Ob += b3 * v3;
    }
#undef SPLAT4
    // combine even/odd partial sums across the half-waves
#pragma unroll
    for (int j = 0; j < 4; ++j) {
        Oa[j] += __shfl_xor(Oa[j], 32);
        Ob[j] += __shfl_xor(Ob[j], 32);
    }
    // half 0 stores row qa, half 1 stores row qb (each covers all 128 dv)
    if (par == 0) {
        f32x4 o = {Oa[0] * ra, Oa[1] * ra, Oa[2] * ra, Oa[3] * ra};
        *(f32x4*)&out[((size_t)b * NQ + q0 + qa) * NDV + dv0] = o;
    } else {
        f32x4 o = {Ob[0] * rb, Ob[1] * rb, Ob[2] * rb, Ob[3] * rb};
        *(f32x4*)&out[((size_t)b * NQ + q0 + qb) * NDV + dv0] = o;
    }
}

extern "C" void kernel_launch(void* const* d_in, const int* in_sizes, int n_in,
                              void* d_out, int out_size, void* d_ws, size_t ws_size,
                              hipStream_t stream) {
    const float* q  = (const float*)d_in[0];  // (16,128,128) f32
    const float* ks = (const float*)d_in[1];  // (16,512,128) f32
    const float* vs = (const float*)d_in[2];  // (16,512,128) f32
    const int*   vl = (const int*)d_in[3];    // (16,) i32
    const float* wq = (const float*)d_in[4];  // (128,128) f32
    const float* wk = (const float*)d_in[5];  // (128,128) f32
    const float* wv = (const float*)d_in[6];  // (128,) f32

    // ws layout (~9.3 MB)
    float* Eq = (float*)d_ws;                     // 2048*128
    float* Ek = Eq + 2048 * 128;                  // 8192*128
    float* P  = Ek + (size_t)8192 * 128;          // 16*128*512
    float* w2 = P + (size_t)NB * NQ * NK;         // 128
    short* pqh = (short*)(w2 + 128);              // 4 x 16384 bf16 frags
    short* pql = pqh + 16384;
    short* pkh = pql + 16384;
    short* pkl = pkh + 16384;

    wsplit_kernel<<<16, 256, 0, stream>>>(wq, wk, wv, pqh, pql, pkh, pkl, w2);
    proj_kernel<<<640, 256, 0, stream>>>(q, ks, pqh, pql, pkh, pkl, Eq, Ek);
    score_kernel<<<512, 512, 0, stream>>>(Eq, Ek, vl, w2, P);
    av_kernel<<<256, 256, 0, stream>>>(P, vs, vl, (float*)d_out);
}

// Round 18
// 104.119 us; speedup vs baseline: 1.0128x; 1.0128x over previous
//
#include <hip/hip_runtime.h>

// Sizes (fixed by the problem)
#define NB 16
#define NQ 128
#define NK 512
#define NH 128
#define NDV 128

#define KPAD 132  // 128+4 floats: b128 lane*KPAD reads measured 0 conflicts

typedef __attribute__((ext_vector_type(8))) short short8;
typedef __attribute__((ext_vector_type(4))) float f32x4;
typedef __attribute__((ext_vector_type(2))) float f32x2;

#define C2LOG2E 2.8853900817779268f  // 2*log2(e): folded into proj epilogue
#define LOG2E   1.4426950408889634f

__device__ __forceinline__ short f2bf(float x) {   // RNE f32 -> bf16
    unsigned u = __float_as_uint(x);
    unsigned r = (u + 0x7fffu + ((u >> 16) & 1u)) >> 16;
    return (short)r;
}
__device__ __forceinline__ float bf2f(short s) {
    return __uint_as_float(((unsigned)(unsigned short)s) << 16);
}

// ---------------------------------------------------------------------------
// FINAL (session-best r16 configuration restored):
//   tanh identity: sum_h wv*tanh(q+k) = Wsum - sum_h 2wv/(Eq*Ek+1),
//   Eq/Ek = exp2(2log2e * proj) precomputed by MFMA projection kernels;
//   masked softmax exploits exact-0 underflow of the -1e6 fill.
// Measured: 104.3us total, of which ~65us is harness re-poison floor.
// ---------------------------------------------------------------------------

// ---------------------------------------------------------------------------
// Kernel 1: pack W into MFMA B-fragment order, split bf16 hi/lo.
// ---------------------------------------------------------------------------
__global__ __launch_bounds__(256) void wsplit_kernel(
    const float* __restrict__ Wq, const float* __restrict__ Wk,
    const float* __restrict__ wv,
    short* __restrict__ pqh, short* __restrict__ pql,
    short* __restrict__ pkh, short* __restrict__ pkl,
    float* __restrict__ w2)
{
    int blk = blockIdx.x;          // 16 blocks = w(2) x ht(8)
    int t   = threadIdx.x;         // ks(4) x lane(64)
    if (blk == 0 && t < NH) w2[t] = 2.0f * wv[t];
    int w = blk >> 3, ht = blk & 7;
    int ks = t >> 6, lane = t & 63;
    int m = lane & 15, quad = lane >> 4;
    const float* W = w ? Wk : Wq;
    short* ph = w ? pkh : pqh;
    short* pl = w ? pkl : pql;
    short8 hi, lo;
#pragma unroll
    for (int j = 0; j < 8; ++j) {
        float x = W[(size_t)(ks * 32 + quad * 8 + j) * NH + ht * 16 + m];
        short h = f2bf(x);
        hi[j] = h;
        lo[j] = f2bf(x - bf2f(h));
    }
    size_t o = (size_t)((ht * 4 + ks) * 64 + lane) * 8;
    *(short8*)(ph + o) = hi;
    *(short8*)(pl + o) = lo;
}

// ---------------------------------------------------------------------------
// Kernel 2: projection + exp. E = exp2(2log2e * X@W), split-bf16 MFMA
// (Ah*Bh + Al*Bh + Ah*Bl, rel err ~2^-16). X tile staged once in LDS.
// ---------------------------------------------------------------------------
__global__ __launch_bounds__(256) void proj_kernel(
    const float* __restrict__ Xq, const float* __restrict__ Xk,
    const short* __restrict__ pqh, const short* __restrict__ pql,
    const short* __restrict__ pkh, const short* __restrict__ pkl,
    float* __restrict__ Eq, float* __restrict__ Ek)
{
    __shared__ float s_x[16 * KPAD];     // 8448 B

    int blk = blockIdx.x;
    const float* X; const short* ph; const short* pl; float* Y; int row0;
    if (blk < 128) { X = Xq; ph = pqh; pl = pql; Y = Eq; row0 = blk * 16; }
    else           { X = Xk; ph = pkh; pl = pkl; Y = Ek; row0 = (blk - 128) * 16; }
    int t = threadIdx.x;
    int wave = t >> 6, lane = t & 63;
    int m = lane & 15, quad = lane >> 4;

#pragma unroll
    for (int r = 0; r < 2; ++r) {
        int i = (t + r * 256) * 4;
        int row = i >> 7, col = i & 127;
        *(f32x4*)&s_x[row * KPAD + col] =
            *(const f32x4*)&X[(size_t)(row0 + row) * NH + col];
    }
    __syncthreads();

    short8 AH[4], AL[4];
#pragma unroll
    for (int ks = 0; ks < 4; ++ks) {
        int base = m * KPAD + ks * 32 + quad * 8;
        f32x4 x0 = *(const f32x4*)&s_x[base];
        f32x4 x1 = *(const f32x4*)&s_x[base + 4];
#pragma unroll
        for (int j = 0; j < 4; ++j) {
            short h0 = f2bf(x0[j]);
            AH[ks][j] = h0; AL[ks][j] = f2bf(x0[j] - bf2f(h0));
            short h1 = f2bf(x1[j]);
            AH[ks][j + 4] = h1; AL[ks][j + 4] = f2bf(x1[j] - bf2f(h1));
        }
    }
#pragma unroll
    for (int hi = 0; hi < 2; ++hi) {
        int ht = wave * 2 + hi;
        f32x4 acc = {0.f, 0.f, 0.f, 0.f};
#pragma unroll
        for (int ks = 0; ks < 4; ++ks) {
            size_t o = (size_t)((ht * 4 + ks) * 64 + lane) * 8;
            short8 bh = *(const short8*)(ph + o);
            short8 bl = *(const short8*)(pl + o);
            acc = __builtin_amdgcn_mfma_f32_16x16x32_bf16(AH[ks], bl, acc, 0, 0, 0);
            acc = __builtin_amdgcn_mfma_f32_16x16x32_bf16(AL[ks], bh, acc, 0, 0, 0);
            acc = __builtin_amdgcn_mfma_f32_16x16x32_bf16(AH[ks], bh, acc, 0, 0, 0);
        }
        // D: col = lane&15, row = quad*4 + r  [verified layout]
#pragma unroll
        for (int r = 0; r < 4; ++r)
            Y[(size_t)(row0 + quad * 4 + r) * NH + ht * 16 + m] =
                __builtin_amdgcn_exp2f(acc[r] * C2LOG2E);
    }
}

// ---------------------------------------------------------------------------
// Kernel 3: scores. Packed-f32 inner loop (v_pk_fma_f32/v_pk_mul_f32 on
// gfx950, -2.8us measured r16) + pair-reciprocal (1 rcp / 2 elems).
// ---------------------------------------------------------------------------
__global__ __launch_bounds__(512) void score_kernel(
    const float* __restrict__ Eqp, const float* __restrict__ Ekp,
    const int* __restrict__ vlen, const float* __restrict__ w2,
    float* __restrict__ P)
{
    __shared__ float s_ek[128 * KPAD];   // 67584 B
    __shared__ float s_eq[16 * NH];      //  8192 B
    __shared__ float s_w2[NH];           //   512 B

    int blk = blockIdx.x;
    int b    = blk & 15;                 // batch-interleaved
    int rest = blk >> 4;
    int qt = rest & 7, kc = rest >> 3;   // qt 0..7 (16q each), kc 0..3 (128k)
    int q0 = qt * 16, k0 = kc * 128;
    int t  = threadIdx.x;

    int nv = vlen[b];
    nv = max(1, min(NK, nv));
    float* Pb = P + ((size_t)b * NQ + q0) * NK;

    if (k0 >= nv) {
        // fully masked chunk: 16q x 128k = 2048 floats = one f32x4/thread
        int q = t >> 5, kk = (t & 31) * 4;
        f32x4 z = {0.f, 0.f, 0.f, 0.f};
        *(f32x4*)&Pb[(size_t)q * NK + k0 + kk] = z;
        return;
    }

    for (int i = t; i < 128 * 32; i += 512) {
        int row = i >> 5, c4 = i & 31;
        *(f32x4*)&s_ek[row * KPAD + c4 * 4] =
            *(const f32x4*)&Ekp[((size_t)b * NK + k0 + row) * NH + c4 * 4];
    }
    *(f32x4*)&s_eq[t * 4] =
        *(const f32x4*)&Eqp[((size_t)b * NQ + q0) * NH + t * 4];
    if (t < 32) *(f32x4*)&s_w2[t * 4] = *(const f32x4*)&w2[t * 4];
    __syncthreads();

    int lane = t & 63, w = t >> 6;
    int g = w & 3, hf = w >> 2;

    // Wsum = sum_h wv = 0.5 * sum_h w2
    float s2 = s_w2[lane] + s_w2[lane + 64];
#pragma unroll
    for (int off = 32; off; off >>= 1) s2 += __shfl_xor(s2, off);
    float wsum = 0.5f * s2;

    const float* ek = &s_ek[(hf * 64 + lane) * KPAD];
    const float* e0 = &s_eq[(g * 4 + 0) * NH];
    const float* e1 = &s_eq[(g * 4 + 1) * NH];
    const float* e2 = &s_eq[(g * 4 + 2) * NH];
    const float* e3 = &s_eq[(g * 4 + 3) * NH];

    const f32x2 one2 = {1.0f, 1.0f};
    f32x2 v00 = {0.f, 0.f}, v01 = {0.f, 0.f};
    f32x2 v10 = {0.f, 0.f}, v11 = {0.f, 0.f};
    f32x2 v20 = {0.f, 0.f}, v21 = {0.f, 0.f};
    f32x2 v30 = {0.f, 0.f}, v31 = {0.f, 0.f};

#define PKSTEP(accv, qv, kv, wv)                                        \
    {                                                                   \
        f32x2 x = qv * kv + one2;                                       \
        float R = __builtin_amdgcn_rcpf(x[0] * x[1]);                   \
        f32x2 xs = {x[1], x[0]};                                        \
        accv += wv * (R * xs);                                          \
    }

#pragma unroll
    for (int hh = 0; hh < NH; hh += 8) {
        f32x4 kAv = *(const f32x4*)(ek + hh);
        f32x4 kBv = *(const f32x4*)(ek + hh + 4);
        f32x4 wAv = *(const f32x4*)(s_w2 + hh);
        f32x4 wBv = *(const f32x4*)(s_w2 + hh + 4);
        f32x2 kA0 = {kAv[0], kAv[1]}, kA1 = {kAv[2], kAv[3]};
        f32x2 kB0 = {kBv[0], kBv[1]}, kB1 = {kBv[2], kBv[3]};
        f32x2 wA0 = {wAv[0], wAv[1]}, wA1 = {wAv[2], wAv[3]};
        f32x2 wB0 = {wBv[0], wBv[1]}, wB1 = {wBv[2], wBv[3]};
        {
            f32x4 qa = *(const f32x4*)(e0 + hh), qb = *(const f32x4*)(e0 + hh + 4);
            f32x2 qa0 = {qa[0], qa[1]}, qa1 = {qa[2], qa[3]};
            f32x2 qb0 = {qb[0], qb[1]}, qb1 = {qb[2], qb[3]};
            PKSTEP(v00, qa0, kA0, wA0); PKSTEP(v01, qa1, kA1, wA1);
            PKSTEP(v00, qb0, kB0, wB0); PKSTEP(v01, qb1, kB1, wB1);
        }
        {
            f32x4 qa = *(const f32x4*)(e1 + hh), qb = *(const f32x4*)(e1 + hh + 4);
            f32x2 qa0 = {qa[0], qa[1]}, qa1 = {qa[2], qa[3]};
            f32x2 qb0 = {qb[0], qb[1]}, qb1 = {qb[2], qb[3]};
            PKSTEP(v10, qa0, kA0, wA0); PKSTEP(v11, qa1, kA1, wA1);
            PKSTEP(v10, qb0, kB0, wB0); PKSTEP(v11, qb1, kB1, wB1);
        }
        {
            f32x4 qa = *(const f32x4*)(e2 + hh), qb = *(const f32x4*)(e2 + hh + 4);
            f32x2 qa0 = {qa[0], qa[1]}, qa1 = {qa[2], qa[3]};
            f32x2 qb0 = {qb[0], qb[1]}, qb1 = {qb[2], qb[3]};
            PKSTEP(v20, qa0, kA0, wA0); PKSTEP(v21, qa1, kA1, wA1);
            PKSTEP(v20, qb0, kB0, wB0); PKSTEP(v21, qb1, kB1, wB1);
        }
        {
            f32x4 qa = *(const f32x4*)(e3 + hh), qb = *(const f32x4*)(e3 + hh + 4);
            f32x2 qa0 = {qa[0], qa[1]}, qa1 = {qa[2], qa[3]};
            f32x2 qb0 = {qb[0], qb[1]}, qb1 = {qb[2], qb[3]};
            PKSTEP(v30, qa0, kA0, wA0); PKSTEP(v31, qa1, kA1, wA1);
            PKSTEP(v30, qb0, kB0, wB0); PKSTEP(v31, qb1, kB1, wB1);
        }
    }
#undef PKSTEP
    float c0 = (v00[0] + v00[1]) + (v01[0] + v01[1]);
    float c1 = (v10[0] + v10[1]) + (v11[0] + v11[1]);
    float c2 = (v20[0] + v20[1]) + (v21[0] + v21[1]);
    float c3 = (v30[0] + v30[1]) + (v31[0] + v31[1]);
    int kg = k0 + hf * 64 + lane;
    bool valid = kg < nv;
    float p0 = valid ? __builtin_amdgcn_exp2f((wsum - c0) * LOG2E) : 0.f;
    float p1 = valid ? __builtin_amdgcn_exp2f((wsum - c1) * LOG2E) : 0.f;
    float p2 = valid ? __builtin_amdgcn_exp2f((wsum - c2) * LOG2E) : 0.f;
    float p3 = valid ? __builtin_amdgcn_exp2f((wsum - c3) * LOG2E) : 0.f;
    float* Pr = Pb + (size_t)(g * 4) * NK + kg;
    Pr[0 * NK] = p0;                     // coalesced dword stores per q-row
    Pr[1 * NK] = p1;
    Pr[2 * NK] = p2;
    Pr[3 * NK] = p3;
}

// ---------------------------------------------------------------------------
// Kernel 4: normalize + AV. r10/r16 form (scalar fmaf chains — r17's packed
// variant measured neutral-to-worse: this loop is V-load-latency bound).
// ---------------------------------------------------------------------------
__global__ __launch_bounds__(256) void av_kernel(
    const float* __restrict__ P, const float* __restrict__ V,
    const int* __restrict__ vlen, float* __restrict__ out)
{
    __shared__ float s_p[8 * NK];        // 16 KB

    int blk = blockIdx.x;
    int b = blk & 15, qt = blk >> 4;     // qt 0..15 (8 q each)
    int q0 = qt * 8;
    int t = threadIdx.x;

    int nv = vlen[b];
    nv = max(1, min(NK, nv));
    int nv8 = (nv + 7) & ~7;

    const f32x4* Pv = (const f32x4*)(P + ((size_t)b * NQ + q0) * NK);
#pragma unroll
    for (int r = 0; r < 4; ++r)
        ((f32x4*)s_p)[t + r * 256] = Pv[t + r * 256];
    __syncthreads();

    int lane = t & 63, w = t >> 6;
    int qa = w * 2, qb = qa + 1;
    const float* pa = &s_p[qa * NK];
    const float* pb = &s_p[qb * NK];

    // row sums (zeros beyond nv included -> exact)
    f32x4 sa0 = *(const f32x4*)(pa + lane * 8);
    f32x4 sa1 = *(const f32x4*)(pa + lane * 8 + 4);
    f32x4 sb0 = *(const f32x4*)(pb + lane * 8);
    f32x4 sb1 = *(const f32x4*)(pb + lane * 8 + 4);
    float sa = ((sa0[0] + sa0[1]) + (sa0[2] + sa0[3])) +
               ((sa1[0] + sa1[1]) + (sa1[2] + sa1[3]));
    float sb = ((sb0[0] + sb0[1]) + (sb0[2] + sb0[3])) +
               ((sb1[0] + sb1[1]) + (sb1[2] + sb1[3]));
#pragma unroll
    for (int off = 32; off; off >>= 1) {
        sa += __shfl_xor(sa, off);
        sb += __shfl_xor(sb, off);
    }
    float ra = 1.0f / sa, rb = 1.0f / sb;

    int par = lane >> 5;                 // k parity for this half-wave
    int dl  = lane & 31;
    int dv0 = dl * 4;                    // 4 dv per lane (f32x4)
    const float* Vb = V + (size_t)b * NK * NDV + dv0;
    f32x4 Oa = {0.f, 0.f, 0.f, 0.f};
    f32x4 Ob = {0.f, 0.f, 0.f, 0.f};
    for (int k = 0; k < nv8; k += 8) {
        f32x4 pA0 = *(const f32x4*)(pa + k);         // LDS broadcasts
        f32x4 pA1 = *(const f32x4*)(pa + k + 4);
        f32x4 pB0 = *(const f32x4*)(pb + k);
        f32x4 pB1 = *(const f32x4*)(pb + k + 4);
        f32x4 v0 = *(const f32x4*)(Vb + (size_t)(k + 0 + par) * NDV);
        f32x4 v1 = *(const f32x4*)(Vb + (size_t)(k + 2 + par) * NDV);
        f32x4 v2 = *(const f32x4*)(Vb + (size_t)(k + 4 + par) * NDV);
        f32x4 v3 = *(const f32x4*)(Vb + (size_t)(k + 6 + par) * NDV);
        float a0 = pA0[par], a1 = pA0[2 + par], a2 = pA1[par], a3 = pA1[2 + par];
        float b0 = pB0[par], b1 = pB0[2 + par], b2 = pB1[par], b3 = pB1[2 + par];
#pragma unroll
        for (int j = 0; j < 4; ++j) {
            Oa[j] = fmaf(a0, v0[j], Oa[j]); Ob[j] = fmaf(b0, v0[j], Ob[j]);
            Oa[j] = fmaf(a1, v1[j], Oa[j]); Ob[j] = fmaf(b1, v1[j], Ob[j]);
            Oa[j] = fmaf(a2, v2[j], Oa[j]); Ob[j] = fmaf(b2, v2[j], Ob[j]);
            Oa[j] = fmaf(a3, v3[j], Oa[j]); Ob[j] = fmaf(b3, v3[j], Ob[j]);
        }
    }
    // combine even/odd partial sums across the half-waves
#pragma unroll
    for (int j = 0; j < 4; ++j) {
        Oa[j] += __shfl_xor(Oa[j], 32);
        Ob[j] += __shfl_xor(Ob[j], 32);
    }
    // half 0 stores row qa, half 1 stores row qb (each covers all 128 dv)
    if (par == 0) {
        f32x4 o = {Oa[0] * ra, Oa[1] * ra, Oa[2] * ra, Oa[3] * ra};
        *(f32x4*)&out[((size_t)b * NQ + q0 + qa) * NDV + dv0] = o;
    } else {
        f32x4 o = {Ob[0] * rb, Ob[1] * rb, Ob[2] * rb, Ob[3] * rb};
        *(f32x4*)&out[((size_t)b * NQ + q0 + qb) * NDV + dv0] = o;
    }
}

extern "C" void kernel_launch(void* const* d_in, const int* in_sizes, int n_in,
                              void* d_out, int out_size, void* d_ws, size_t ws_size,
                              hipStream_t stream) {
    const float* q  = (const float*)d_in[0];  // (16,128,128) f32
    const float* ks = (const float*)d_in[1];  // (16,512,128) f32
    const float* vs = (const float*)d_in[2];  // (16,512,128) f32
    const int*   vl = (const int*)d_in[3];    // (16,) i32
    const float* wq = (const float*)d_in[4];  // (128,128) f32
    const float* wk = (const float*)d_in[5];  // (128,128) f32
    const float* wv = (const float*)d_in[6];  // (128,) f32

    // ws layout (~9.3 MB)
    float* Eq = (float*)d_ws;                     // 2048*128
    float* Ek = Eq + 2048 * 128;                  // 8192*128
    float* P  = Ek + (size_t)8192 * 128;          // 16*128*512
    float* w2 = P + (size_t)NB * NQ * NK;         // 128
    short* pqh = (short*)(w2 + 128);              // 4 x 16384 bf16 frags
    short* pql = pqh + 16384;
    short* pkh = pql + 16384;
    short* pkl = pkh + 16384;

    wsplit_kernel<<<16, 256, 0, stream>>>(wq, wk, wv, pqh, pql, pkh, pkl, w2);
    proj_kernel<<<640, 256, 0, stream>>>(q, ks, pqh, pql, pkh, pkl, Eq, Ek);
    score_kernel<<<512, 512, 0, stream>>>(Eq, Ek, vl, w2, P);
    av_kernel<<<256, 256, 0, stream>>>(P, vs, vl, (float*)d_out);
}